// Round 14
// baseline (67.491 us; speedup 1.0000x reference)
//
#include <hip/hip_runtime.h>

// Local windowed 2D autocorrelation.
// x: [8, 64, 128, 128] fp32; out: [8, 64, 31, 31, 8, 8] fp32.
// KH=KW=8, SH=SW=4, no padding.
//
// Round 14 = round 13 + __launch_bounds__(256, 1).
// Round 13 post-mortem: compiler CHOSE VGPR=88 (occupancy heuristic, no
// min-waves hint) < ~110 live set -> 24 floats/thread scratch spill
// (WRITE 172MB vs 123MB) + 18KB LDS spill with 3.2M bank conflicts.
// launch_bounds(256,1) lifts the cap to 256 -- the allocator must hold the
// live set (round-2 lesson, this time the compiler's default was the
// offender, not my explicit cap).
//
// Design: ONE WAVE COMPUTES ALL 64 OFFSETS of its 62 windows -> loads per
// tile drop 5x (80KB -> 16KB through TA/L1; rounds 8/9/12 proved occupancy
// is not the limiter, pipe accounting says TA redundancy ~14us).
// Carried: packed fp32 FMA (round 10); symmetry corr(dy,dx)=corr(-dy,-dx)
// (40 of 64 values computed); LDS assembly + contiguous full-line copy-out
// (round 5: scattered 32B stores = 3.75x write amp); XOR-swizzle (w&7);
// block = 4 waves = 4 adjacent hp-pairs -> one contiguous 63.5KB run.

#define NH 31
#define NW 31

typedef float f32x4 __attribute__((ext_vector_type(4)));
typedef float f32x2 __attribute__((ext_vector_type(2)));

// Row task for dy = -D (output rows oy=4-D and mirror 4+D), D in 1..4.
// acc2[p] = {acc[2p], acc[2p+1]}, acc[ox] = sum_{i>=D, j} R[i][j]*R[i-D][j+ox-4].
// e (if WE) = mirror-row edge value (ox=0 of row 4+D).
template <int D, bool WE>
__device__ __forceinline__ void corr_rows(const float (&R)[8][8], f32x2 acc2[4], float& e) {
  f32x2 e2 = {0.f, 0.f};
#pragma unroll
  for (int i = D; i < 8; ++i) {
    const float(&ra)[8] = R[i];
    const float(&rb)[8] = R[i - D];
#pragma unroll
    for (int p = 0; p < 4; ++p) {
      const int j0 = (4 - 2 * p) > 0 ? (4 - 2 * p) : 0;
      const int j1 = (10 - 2 * p) < 7 ? (10 - 2 * p) : 7;
#pragma unroll
      for (int j = j0; j <= j1; ++j) {
        f32x2 a = {ra[j], ra[j]};
        f32x2 b = {rb[j + 2 * p - 4], rb[j + 2 * p - 3]};
        acc2[p] = __builtin_elementwise_fma(a, b, acc2[p]);
      }
    }
    acc2[0].y = fmaf(ra[3], rb[0], acc2[0].y);  // ox=1, j=3
    acc2[1].y = fmaf(ra[1], rb[0], acc2[1].y);  // ox=3, j=1
    acc2[2].x = fmaf(ra[7], rb[7], acc2[2].x);  // ox=4, j=7
    acc2[3].x = fmaf(ra[5], rb[7], acc2[3].x);  // ox=6, j=5
    if (WE) {
      f32x2 b0 = {rb[4], rb[5]}, a0 = {ra[0], ra[1]};
      f32x2 b1 = {rb[6], rb[7]}, a1 = {ra[2], ra[3]};
      e2 = __builtin_elementwise_fma(b0, a0, e2);
      e2 = __builtin_elementwise_fma(b1, a1, e2);
    }
  }
  if (WE) e = e2.x + e2.y;
}

// dy = 0 task: acc2[0]={acc[0],acc[1]}, acc2[1]={acc[2],acc[3]}, a4=acc[4].
__device__ __forceinline__ void corr_rows0(const float (&R)[8][8], f32x2 acc2[2], float& a4) {
  f32x2 s2 = {0.f, 0.f};
#pragma unroll
  for (int i = 0; i < 8; ++i) {
    const float(&r)[8] = R[i];
#pragma unroll
    for (int j = 4; j <= 7; ++j) {
      f32x2 a = {r[j], r[j]};
      f32x2 b = {r[j - 4], r[j - 3]};
      acc2[0] = __builtin_elementwise_fma(a, b, acc2[0]);
    }
    acc2[0].y = fmaf(r[3], r[0], acc2[0].y);
#pragma unroll
    for (int j = 2; j <= 7; ++j) {
      f32x2 a = {r[j], r[j]};
      f32x2 b = {r[j - 2], r[j - 1]};
      acc2[1] = __builtin_elementwise_fma(a, b, acc2[1]);
    }
    acc2[1].y = fmaf(r[1], r[0], acc2[1].y);
#pragma unroll
    for (int j = 0; j < 8; j += 2) {
      f32x2 v = {r[j], r[j + 1]};
      s2 = __builtin_elementwise_fma(v, v, s2);
    }
  }
  a4 = s2.x + s2.y;
}

__global__ __launch_bounds__(256, 1) void lacorr2d_kernel(
    const float* __restrict__ x, float* __restrict__ out) {
  __shared__ __align__(16) float lds[8][31][64];  // 63.5 KB

  const int g    = threadIdx.x >> 6;   // wave 0..3 -> hp-pair within quad
  const int lane = threadIdx.x & 63;
  const int w    = lane & 31;          // window col (31 = dead lane)
  const int hh   = lane >> 5;          // 0/1 within window-row pair

  const int q  = blockIdx.x & 3;       // hp quad
  const int bc = blockIdx.x >> 2;      // 0..511
  const int hp = q * 4 + g;            // window-row pair 0..15
  const int h  = hp * 2 + hh;          // 0..31 (31 invalid)
  const bool valid = (w < NW) && (h < NH);
  const int hc = valid ? h : 0;
  const int wc = valid ? w : 0;

  const float* src = x + (size_t)bc * (128 * 128) + (size_t)(hc * 4) * 128 + wc * 4;
  float* wbase = &lds[2 * g + hh][wc][0];
  const int sw = wc & 7;  // swizzle key

  // Load the whole 8x8 window ONCE (16 independent float4 loads).
  float R[8][8];
#pragma unroll
  for (int i = 0; i < 8; ++i) {
    f32x4 a = *reinterpret_cast<const f32x4*>(src + i * 128);
    f32x4 b = *reinterpret_cast<const f32x4*>(src + i * 128 + 4);
    R[i][0] = a.x; R[i][1] = a.y; R[i][2] = a.z; R[i][3] = a.w;
    R[i][4] = b.x; R[i][5] = b.y; R[i][6] = b.z; R[i][7] = b.w;
  }

#define LDS_ST(e4, a, b, c, d)                                              \
  do {                                                                      \
    f32x4 v_ = {a, b, c, d};                                                \
    *reinterpret_cast<f32x4*>(wbase + (((e4) ^ sw) << 2)) = v_;             \
  } while (0)

  {  // D4: row 0 (no mirror)
    f32x2 acc2[4] = {{0.f, 0.f}, {0.f, 0.f}, {0.f, 0.f}, {0.f, 0.f}};
    float e = 0.f;
    corr_rows<4, false>(R, acc2, e);
    if (valid) {
      LDS_ST(0, acc2[0].x, acc2[0].y, acc2[1].x, acc2[1].y);
      LDS_ST(1, acc2[2].x, acc2[2].y, acc2[3].x, acc2[3].y);
    }
  }
  __builtin_amdgcn_sched_barrier(0);
  {  // D3: rows 1 & 7
    f32x2 acc2[4] = {{0.f, 0.f}, {0.f, 0.f}, {0.f, 0.f}, {0.f, 0.f}};
    float e = 0.f;
    corr_rows<3, true>(R, acc2, e);
    if (valid) {
      LDS_ST(2,  acc2[0].x, acc2[0].y, acc2[1].x, acc2[1].y);
      LDS_ST(3,  acc2[2].x, acc2[2].y, acc2[3].x, acc2[3].y);
      LDS_ST(14, e,         acc2[3].y, acc2[3].x, acc2[2].y);
      LDS_ST(15, acc2[2].x, acc2[1].y, acc2[1].x, acc2[0].y);
    }
  }
  __builtin_amdgcn_sched_barrier(0);
  {  // D2: rows 2 & 6
    f32x2 acc2[4] = {{0.f, 0.f}, {0.f, 0.f}, {0.f, 0.f}, {0.f, 0.f}};
    float e = 0.f;
    corr_rows<2, true>(R, acc2, e);
    if (valid) {
      LDS_ST(4,  acc2[0].x, acc2[0].y, acc2[1].x, acc2[1].y);
      LDS_ST(5,  acc2[2].x, acc2[2].y, acc2[3].x, acc2[3].y);
      LDS_ST(12, e,         acc2[3].y, acc2[3].x, acc2[2].y);
      LDS_ST(13, acc2[2].x, acc2[1].y, acc2[1].x, acc2[0].y);
    }
  }
  __builtin_amdgcn_sched_barrier(0);
  {  // D1: rows 3 & 5
    f32x2 acc2[4] = {{0.f, 0.f}, {0.f, 0.f}, {0.f, 0.f}, {0.f, 0.f}};
    float e = 0.f;
    corr_rows<1, true>(R, acc2, e);
    if (valid) {
      LDS_ST(6,  acc2[0].x, acc2[0].y, acc2[1].x, acc2[1].y);
      LDS_ST(7,  acc2[2].x, acc2[2].y, acc2[3].x, acc2[3].y);
      LDS_ST(10, e,         acc2[3].y, acc2[3].x, acc2[2].y);
      LDS_ST(11, acc2[2].x, acc2[1].y, acc2[1].x, acc2[0].y);
    }
  }
  __builtin_amdgcn_sched_barrier(0);
  {  // D0: row 4 (self-mirrored)
    f32x2 acc2[2] = {{0.f, 0.f}, {0.f, 0.f}};
    float a4 = 0.f;
    corr_rows0(R, acc2, a4);
    if (valid) {
      LDS_ST(8, acc2[0].x, acc2[0].y, acc2[1].x, acc2[1].y);
      LDS_ST(9, a4,        acc2[1].y, acc2[1].x, acc2[0].y);
    }
  }
#undef LDS_ST

  __syncthreads();

  // Copy out the block's 8 window-rows (7 for q=3: row 31 doesn't exist)
  // as ONE contiguous run: nrows*31*256 B, full lines, lane-consecutive.
  const int nrows = (q == 3) ? 7 : 8;
  float* orun = out + (size_t)(bc * NH + q * 8) * (NW * 64);
  const int total = nrows * NW * 16;  // float4 count
  for (int idx = threadIdx.x; idx < total; idx += 256) {
    const int f4 = idx >> 4;
    const int hr = f4 / NW;
    const int ww = f4 % NW;
    const int e4 = idx & 15;
    f32x4 v = *reinterpret_cast<const f32x4*>(&lds[hr][ww][(e4 ^ (ww & 7)) << 2]);
    *reinterpret_cast<f32x4*>(orun + (size_t)idx * 4) = v;
  }
}

extern "C" void kernel_launch(void* const* d_in, const int* in_sizes, int n_in,
                              void* d_out, int out_size, void* d_ws, size_t ws_size,
                              hipStream_t stream) {
  const float* x = (const float*)d_in[0];
  float* out = (float*)d_out;
  // 512 bc-planes x 4 hp-quads
  lacorr2d_kernel<<<512 * 4, 256, 0, stream>>>(x, out);
}

// Round 15
// 32.834 us; speedup vs baseline: 2.0555x; 2.0555x over previous
//
#include <hip/hip_runtime.h>

// Local windowed 2D autocorrelation.
// x: [8, 64, 128, 128] fp32; out: [8, 64, 31, 31, 8, 8] fp32.
// KH=KW=8, SH=SW=4, no padding.
//
// Round 15: one wave computes ALL 64 offsets (5x TA-load reduction vs the
// 42us round-10 kernel), restructured to be SROA-PROOF. Rounds 13/14
// post-mortem: kernel-scope R[8][8] + 5 sections + sched_barrier(0) defeated
// SROA -> AMDGPUPromoteAlloca pushed the array into LDS (declared 63488,
// reported 81920, 3.2M bank conflicts) and scratch (WRITE 172MB vs 123MB).
// Now: a single fully-unrolled row sweep over NAMED f32x4 row variables
// (rl0..rh7, no kernel-scope arrays, no address-taken, no sched_barriers);
// at row i all applicable D-tasks update (rows i, i-D). SSA liveness rolls:
// row 0 dies after i=4 -> ~110 live VGPR. Arrays appear only as tiny
// constant-indexed locals inside __forceinline__ helpers (the pattern that
// SROA'd cleanly in rounds 10-12: LDS exact, 0 conflicts).
//
// Carried: packed fp32 FMA (round 10: 61->42us); symmetry (40 of 64 values
// computed, mirrors via reversal + edge); LDS result assembly + contiguous
// full-line copy-out (round 5: scattered 32B stores = 3.75x write amp);
// XOR-swizzle (w&7); block = 4 waves = 4 adjacent hp-pairs -> one
// contiguous 63.5KB output run (round 12 structure).
// Tripwires: LDS_Block_Size must be 63488, WRITE_SIZE must be 123008 KB.

#define NH 31
#define NW 31

typedef float f32x4 __attribute__((ext_vector_type(4)));
typedef float f32x2 __attribute__((ext_vector_type(2)));

// One row-pair update for task D>=1: rows a (=row i) and b (=row i-D).
// P0..P3 = packed acc {ox=2p, 2p+1}; E = packed mirror-edge acc (if WE).
template <bool WE>
__device__ __forceinline__ void stepW(f32x4 al, f32x4 ah, f32x4 bl, f32x4 bh,
                                      f32x2& P0, f32x2& P1, f32x2& P2, f32x2& P3,
                                      f32x2& E) {
  float a[8] = {al.x, al.y, al.z, al.w, ah.x, ah.y, ah.z, ah.w};
  float b[8] = {bl.x, bl.y, bl.z, bl.w, bh.x, bh.y, bh.z, bh.w};
  f32x2 p0 = P0, p1 = P1, p2 = P2, p3 = P3;
#pragma unroll
  for (int j = 4; j <= 7; ++j) {  // pair p=0 (ox 0,1)
    f32x2 av = {a[j], a[j]};
    f32x2 bv = {b[j - 4], b[j - 3]};
    p0 = __builtin_elementwise_fma(av, bv, p0);
  }
#pragma unroll
  for (int j = 2; j <= 7; ++j) {  // pair p=1 (ox 2,3)
    f32x2 av = {a[j], a[j]};
    f32x2 bv = {b[j - 2], b[j - 1]};
    p1 = __builtin_elementwise_fma(av, bv, p1);
  }
#pragma unroll
  for (int j = 0; j <= 6; ++j) {  // pair p=2 (ox 4,5)
    f32x2 av = {a[j], a[j]};
    f32x2 bv = {b[j], b[j + 1]};
    p2 = __builtin_elementwise_fma(av, bv, p2);
  }
#pragma unroll
  for (int j = 0; j <= 4; ++j) {  // pair p=3 (ox 6,7)
    f32x2 av = {a[j], a[j]};
    f32x2 bv = {b[j + 2], b[j + 3]};
    p3 = __builtin_elementwise_fma(av, bv, p3);
  }
  p0.y = fmaf(a[3], b[0], p0.y);  // ox=1, j=3
  p1.y = fmaf(a[1], b[0], p1.y);  // ox=3, j=1
  p2.x = fmaf(a[7], b[7], p2.x);  // ox=4, j=7
  p3.x = fmaf(a[5], b[7], p3.x);  // ox=6, j=5
  if (WE) {
    f32x2 b0 = {b[4], b[5]}, a0 = {a[0], a[1]};
    f32x2 b1 = {b[6], b[7]}, a1 = {a[2], a[3]};
    E = __builtin_elementwise_fma(b0, a0, E);
    E = __builtin_elementwise_fma(b1, a1, E);
  }
  P0 = p0; P1 = p1; P2 = p2; P3 = p3;
}

// D=0 update for one row: only ox 0..4 (row 4 is self-mirrored).
__device__ __forceinline__ void step0(f32x4 al, f32x4 ah,
                                      f32x2& P0, f32x2& P1, f32x2& S) {
  float r[8] = {al.x, al.y, al.z, al.w, ah.x, ah.y, ah.z, ah.w};
  f32x2 p0 = P0, p1 = P1, s = S;
#pragma unroll
  for (int j = 4; j <= 7; ++j) {
    f32x2 av = {r[j], r[j]};
    f32x2 bv = {r[j - 4], r[j - 3]};
    p0 = __builtin_elementwise_fma(av, bv, p0);
  }
  p0.y = fmaf(r[3], r[0], p0.y);
#pragma unroll
  for (int j = 2; j <= 7; ++j) {
    f32x2 av = {r[j], r[j]};
    f32x2 bv = {r[j - 2], r[j - 1]};
    p1 = __builtin_elementwise_fma(av, bv, p1);
  }
  p1.y = fmaf(r[1], r[0], p1.y);
#pragma unroll
  for (int j = 0; j < 8; j += 2) {
    f32x2 v = {r[j], r[j + 1]};
    s = __builtin_elementwise_fma(v, v, s);
  }
  P0 = p0; P1 = p1; S = s;
}

__global__ __launch_bounds__(256, 1) void lacorr2d_kernel(
    const float* __restrict__ x, float* __restrict__ out) {
  __shared__ __align__(16) float lds[8][31][64];  // 63.5 KB

  const int g    = threadIdx.x >> 6;   // wave 0..3 -> hp-pair within quad
  const int lane = threadIdx.x & 63;
  const int w    = lane & 31;          // window col (31 = dead lane)
  const int hh   = lane >> 5;          // 0/1 within window-row pair

  const int q  = blockIdx.x & 3;       // hp quad
  const int bc = blockIdx.x >> 2;      // 0..511
  const int hp = q * 4 + g;            // window-row pair 0..15
  const int h  = hp * 2 + hh;          // 0..31 (31 invalid)
  const bool valid = (w < NW) && (h < NH);
  const int hc = valid ? h : 0;
  const int wc = valid ? w : 0;

  const float* src = x + (size_t)bc * (128 * 128) + (size_t)(hc * 4) * 128 + wc * 4;
  float* wbase = &lds[2 * g + hh][wc][0];
  const int sw = wc & 7;  // swizzle key

  // 16 named row-half loads (no arrays -> nothing for PromoteAlloca).
  f32x4 rl0 = *(const f32x4*)(src + 0 * 128), rh0 = *(const f32x4*)(src + 0 * 128 + 4);
  f32x4 rl1 = *(const f32x4*)(src + 1 * 128), rh1 = *(const f32x4*)(src + 1 * 128 + 4);
  f32x4 rl2 = *(const f32x4*)(src + 2 * 128), rh2 = *(const f32x4*)(src + 2 * 128 + 4);
  f32x4 rl3 = *(const f32x4*)(src + 3 * 128), rh3 = *(const f32x4*)(src + 3 * 128 + 4);
  f32x4 rl4 = *(const f32x4*)(src + 4 * 128), rh4 = *(const f32x4*)(src + 4 * 128 + 4);
  f32x4 rl5 = *(const f32x4*)(src + 5 * 128), rh5 = *(const f32x4*)(src + 5 * 128 + 4);
  f32x4 rl6 = *(const f32x4*)(src + 6 * 128), rh6 = *(const f32x4*)(src + 6 * 128 + 4);
  f32x4 rl7 = *(const f32x4*)(src + 7 * 128), rh7 = *(const f32x4*)(src + 7 * 128 + 4);

  // Named packed accumulators (no arrays).
  f32x2 z = {0.f, 0.f};
  f32x2 d4p0 = z, d4p1 = z, d4p2 = z, d4p3 = z;
  f32x2 d3p0 = z, d3p1 = z, d3p2 = z, d3p3 = z, e3 = z;
  f32x2 d2p0 = z, d2p1 = z, d2p2 = z, d2p3 = z, e2 = z;
  f32x2 d1p0 = z, d1p1 = z, d1p2 = z, d1p3 = z, e1 = z;
  f32x2 d0p0 = z, d0p1 = z, s0 = z;
  f32x2 eDummy = z;

  // Single row sweep: at row i update D0(i,i), D1(i,i-1) ... D4(i,i-4).
  step0(rl0, rh0, d0p0, d0p1, s0);

  step0(rl1, rh1, d0p0, d0p1, s0);
  stepW<true>(rl1, rh1, rl0, rh0, d1p0, d1p1, d1p2, d1p3, e1);

  step0(rl2, rh2, d0p0, d0p1, s0);
  stepW<true>(rl2, rh2, rl1, rh1, d1p0, d1p1, d1p2, d1p3, e1);
  stepW<true>(rl2, rh2, rl0, rh0, d2p0, d2p1, d2p2, d2p3, e2);

  step0(rl3, rh3, d0p0, d0p1, s0);
  stepW<true>(rl3, rh3, rl2, rh2, d1p0, d1p1, d1p2, d1p3, e1);
  stepW<true>(rl3, rh3, rl1, rh1, d2p0, d2p1, d2p2, d2p3, e2);
  stepW<true>(rl3, rh3, rl0, rh0, d3p0, d3p1, d3p2, d3p3, e3);

  step0(rl4, rh4, d0p0, d0p1, s0);
  stepW<true>(rl4, rh4, rl3, rh3, d1p0, d1p1, d1p2, d1p3, e1);
  stepW<true>(rl4, rh4, rl2, rh2, d2p0, d2p1, d2p2, d2p3, e2);
  stepW<true>(rl4, rh4, rl1, rh1, d3p0, d3p1, d3p2, d3p3, e3);
  stepW<false>(rl4, rh4, rl0, rh0, d4p0, d4p1, d4p2, d4p3, eDummy);

  step0(rl5, rh5, d0p0, d0p1, s0);
  stepW<true>(rl5, rh5, rl4, rh4, d1p0, d1p1, d1p2, d1p3, e1);
  stepW<true>(rl5, rh5, rl3, rh3, d2p0, d2p1, d2p2, d2p3, e2);
  stepW<true>(rl5, rh5, rl2, rh2, d3p0, d3p1, d3p2, d3p3, e3);
  stepW<false>(rl5, rh5, rl1, rh1, d4p0, d4p1, d4p2, d4p3, eDummy);

  step0(rl6, rh6, d0p0, d0p1, s0);
  stepW<true>(rl6, rh6, rl5, rh5, d1p0, d1p1, d1p2, d1p3, e1);
  stepW<true>(rl6, rh6, rl4, rh4, d2p0, d2p1, d2p2, d2p3, e2);
  stepW<true>(rl6, rh6, rl3, rh3, d3p0, d3p1, d3p2, d3p3, e3);
  stepW<false>(rl6, rh6, rl2, rh2, d4p0, d4p1, d4p2, d4p3, eDummy);

  step0(rl7, rh7, d0p0, d0p1, s0);
  stepW<true>(rl7, rh7, rl6, rh6, d1p0, d1p1, d1p2, d1p3, e1);
  stepW<true>(rl7, rh7, rl5, rh5, d2p0, d2p1, d2p2, d2p3, e2);
  stepW<true>(rl7, rh7, rl4, rh4, d3p0, d3p1, d3p2, d3p3, e3);
  stepW<false>(rl7, rh7, rl3, rh3, d4p0, d4p1, d4p2, d4p3, eDummy);

  const float ev1 = e1.x + e1.y;
  const float ev2 = e2.x + e2.y;
  const float ev3 = e3.x + e3.y;
  const float a4  = s0.x + s0.y;

#define LDS_ST(e4, A, B, C, Dv)                                             \
  do {                                                                      \
    f32x4 v_ = {A, B, C, Dv};                                               \
    *reinterpret_cast<f32x4*>(wbase + (((e4) ^ sw) << 2)) = v_;             \
  } while (0)

  if (valid) {
    // row 0 (oy=0, dy=-4)
    LDS_ST(0,  d4p0.x, d4p0.y, d4p1.x, d4p1.y);
    LDS_ST(1,  d4p2.x, d4p2.y, d4p3.x, d4p3.y);
    // row 1 (dy=-3) + mirror row 7
    LDS_ST(2,  d3p0.x, d3p0.y, d3p1.x, d3p1.y);
    LDS_ST(3,  d3p2.x, d3p2.y, d3p3.x, d3p3.y);
    LDS_ST(14, ev3,    d3p3.y, d3p3.x, d3p2.y);
    LDS_ST(15, d3p2.x, d3p1.y, d3p1.x, d3p0.y);
    // row 2 (dy=-2) + mirror row 6
    LDS_ST(4,  d2p0.x, d2p0.y, d2p1.x, d2p1.y);
    LDS_ST(5,  d2p2.x, d2p2.y, d2p3.x, d2p3.y);
    LDS_ST(12, ev2,    d2p3.y, d2p3.x, d2p2.y);
    LDS_ST(13, d2p2.x, d2p1.y, d2p1.x, d2p0.y);
    // row 3 (dy=-1) + mirror row 5
    LDS_ST(6,  d1p0.x, d1p0.y, d1p1.x, d1p1.y);
    LDS_ST(7,  d1p2.x, d1p2.y, d1p3.x, d1p3.y);
    LDS_ST(10, ev1,    d1p3.y, d1p3.x, d1p2.y);
    LDS_ST(11, d1p2.x, d1p1.y, d1p1.x, d1p0.y);
    // row 4 (dy=0, self-mirrored)
    LDS_ST(8,  d0p0.x, d0p0.y, d0p1.x, d0p1.y);
    LDS_ST(9,  a4,     d0p1.y, d0p1.x, d0p0.y);
  }
#undef LDS_ST

  __syncthreads();

  // Copy out the block's 8 window-rows (7 for q=3: row 31 doesn't exist)
  // as ONE contiguous run: nrows*31*256 B, full lines, lane-consecutive.
  const int nrows = (q == 3) ? 7 : 8;
  float* orun = out + (size_t)(bc * NH + q * 8) * (NW * 64);
  const int total = nrows * NW * 16;  // float4 count
  for (int idx = threadIdx.x; idx < total; idx += 256) {
    const int f4 = idx >> 4;
    const int hr = f4 / NW;
    const int ww = f4 % NW;
    const int e4 = idx & 15;
    f32x4 v = *reinterpret_cast<const f32x4*>(&lds[hr][ww][(e4 ^ (ww & 7)) << 2]);
    *reinterpret_cast<f32x4*>(orun + (size_t)idx * 4) = v;
  }
}

extern "C" void kernel_launch(void* const* d_in, const int* in_sizes, int n_in,
                              void* d_out, int out_size, void* d_ws, size_t ws_size,
                              hipStream_t stream) {
  const float* x = (const float*)d_in[0];
  float* out = (float*)d_out;
  // 512 bc-planes x 4 hp-quads
  lacorr2d_kernel<<<512 * 4, 256, 0, stream>>>(x, out);
}

// Round 16
// 32.298 us; speedup vs baseline: 2.0896x; 1.0166x over previous
//
#include <hip/hip_runtime.h>

// Local windowed 2D autocorrelation.
// x: [8, 64, 128, 128] fp32; out: [8, 64, 31, 31, 8, 8] fp32.
// KH=KW=8, SH=SW=4, no padding.
//
// Round 16 = round 15 (32.8us) MINUS the block-wide barrier.
// Each wave writes/reads ONLY its own 2 LDS planes, so __syncthreads was
// pure over-synchronization: it held every wave's store drain hostage to
// the slowest sibling's compute. Now each wave assembles its 2 output rows
// in its private LDS region and streams them out itself (64 lanes x 16 B
// consecutive = 1 KB/instr, full lines). Same-wave ds_write->ds_read
// ordering is compiler-handled (lgkmcnt), no barrier required. Waves
// pipeline independently -> store drain overlaps sibling compute.
//
// Carried: one wave computes ALL 64 offsets (round 15: 5x TA-load cut,
// 42->32.8us); SROA-proof named f32x4/f32x2 SSA values ONLY at kernel scope
// (rounds 13/14: kernel-scope arrays got PromoteAlloca'd into LDS+scratch:
// +18KB LDS, 3.2M conflicts, +49MB writes); packed fp32 FMA (round 10:
// 61->42us); symmetry corr(dy,dx)=corr(-dy,-dx) (40 of 64 computed);
// LDS assembly + full-line copy-out (round 5: scattered 32B stores =
// 3.75x write amp); XOR-swizzle (w&7) = conflict-free.
// Tripwires: LDS_Block_Size 63488, WRITE_SIZE 123008 KB, conflicts ~0.

#define NH 31
#define NW 31

typedef float f32x4 __attribute__((ext_vector_type(4)));
typedef float f32x2 __attribute__((ext_vector_type(2)));

// One row-pair update for task D>=1: rows a (=row i) and b (=row i-D).
// P0..P3 = packed acc {ox=2p, 2p+1}; E = packed mirror-edge acc (if WE).
template <bool WE>
__device__ __forceinline__ void stepW(f32x4 al, f32x4 ah, f32x4 bl, f32x4 bh,
                                      f32x2& P0, f32x2& P1, f32x2& P2, f32x2& P3,
                                      f32x2& E) {
  float a[8] = {al.x, al.y, al.z, al.w, ah.x, ah.y, ah.z, ah.w};
  float b[8] = {bl.x, bl.y, bl.z, bl.w, bh.x, bh.y, bh.z, bh.w};
  f32x2 p0 = P0, p1 = P1, p2 = P2, p3 = P3;
#pragma unroll
  for (int j = 4; j <= 7; ++j) {  // pair p=0 (ox 0,1)
    f32x2 av = {a[j], a[j]};
    f32x2 bv = {b[j - 4], b[j - 3]};
    p0 = __builtin_elementwise_fma(av, bv, p0);
  }
#pragma unroll
  for (int j = 2; j <= 7; ++j) {  // pair p=1 (ox 2,3)
    f32x2 av = {a[j], a[j]};
    f32x2 bv = {b[j - 2], b[j - 1]};
    p1 = __builtin_elementwise_fma(av, bv, p1);
  }
#pragma unroll
  for (int j = 0; j <= 6; ++j) {  // pair p=2 (ox 4,5)
    f32x2 av = {a[j], a[j]};
    f32x2 bv = {b[j], b[j + 1]};
    p2 = __builtin_elementwise_fma(av, bv, p2);
  }
#pragma unroll
  for (int j = 0; j <= 4; ++j) {  // pair p=3 (ox 6,7)
    f32x2 av = {a[j], a[j]};
    f32x2 bv = {b[j + 2], b[j + 3]};
    p3 = __builtin_elementwise_fma(av, bv, p3);
  }
  p0.y = fmaf(a[3], b[0], p0.y);  // ox=1, j=3
  p1.y = fmaf(a[1], b[0], p1.y);  // ox=3, j=1
  p2.x = fmaf(a[7], b[7], p2.x);  // ox=4, j=7
  p3.x = fmaf(a[5], b[7], p3.x);  // ox=6, j=5
  if (WE) {
    f32x2 b0 = {b[4], b[5]}, a0 = {a[0], a[1]};
    f32x2 b1 = {b[6], b[7]}, a1 = {a[2], a[3]};
    E = __builtin_elementwise_fma(b0, a0, E);
    E = __builtin_elementwise_fma(b1, a1, E);
  }
  P0 = p0; P1 = p1; P2 = p2; P3 = p3;
}

// D=0 update for one row: only ox 0..4 (row 4 is self-mirrored).
__device__ __forceinline__ void step0(f32x4 al, f32x4 ah,
                                      f32x2& P0, f32x2& P1, f32x2& S) {
  float r[8] = {al.x, al.y, al.z, al.w, ah.x, ah.y, ah.z, ah.w};
  f32x2 p0 = P0, p1 = P1, s = S;
#pragma unroll
  for (int j = 4; j <= 7; ++j) {
    f32x2 av = {r[j], r[j]};
    f32x2 bv = {r[j - 4], r[j - 3]};
    p0 = __builtin_elementwise_fma(av, bv, p0);
  }
  p0.y = fmaf(r[3], r[0], p0.y);
#pragma unroll
  for (int j = 2; j <= 7; ++j) {
    f32x2 av = {r[j], r[j]};
    f32x2 bv = {r[j - 2], r[j - 1]};
    p1 = __builtin_elementwise_fma(av, bv, p1);
  }
  p1.y = fmaf(r[1], r[0], p1.y);
#pragma unroll
  for (int j = 0; j < 8; j += 2) {
    f32x2 v = {r[j], r[j + 1]};
    s = __builtin_elementwise_fma(v, v, s);
  }
  P0 = p0; P1 = p1; S = s;
}

__global__ __launch_bounds__(256, 1) void lacorr2d_kernel(
    const float* __restrict__ x, float* __restrict__ out) {
  __shared__ __align__(16) float lds[8][31][64];  // 63.5 KB, 2 planes/wave

  const int g    = threadIdx.x >> 6;   // wave 0..3 -> hp-pair within quad
  const int lane = threadIdx.x & 63;
  const int w    = lane & 31;          // window col (31 = dead lane)
  const int hh   = lane >> 5;          // 0/1 within window-row pair

  const int q  = blockIdx.x & 3;       // hp quad
  const int bc = blockIdx.x >> 2;      // 0..511
  const int hp = q * 4 + g;            // window-row pair 0..15
  const int h  = hp * 2 + hh;          // 0..31 (31 invalid)
  const bool valid = (w < NW) && (h < NH);
  const int hc = valid ? h : 0;
  const int wc = valid ? w : 0;

  const float* src = x + (size_t)bc * (128 * 128) + (size_t)(hc * 4) * 128 + wc * 4;
  float* wbase = &lds[2 * g + hh][wc][0];
  const int sw = wc & 7;  // swizzle key

  // 16 named row-half loads (no arrays -> nothing for PromoteAlloca).
  f32x4 rl0 = *(const f32x4*)(src + 0 * 128), rh0 = *(const f32x4*)(src + 0 * 128 + 4);
  f32x4 rl1 = *(const f32x4*)(src + 1 * 128), rh1 = *(const f32x4*)(src + 1 * 128 + 4);
  f32x4 rl2 = *(const f32x4*)(src + 2 * 128), rh2 = *(const f32x4*)(src + 2 * 128 + 4);
  f32x4 rl3 = *(const f32x4*)(src + 3 * 128), rh3 = *(const f32x4*)(src + 3 * 128 + 4);
  f32x4 rl4 = *(const f32x4*)(src + 4 * 128), rh4 = *(const f32x4*)(src + 4 * 128 + 4);
  f32x4 rl5 = *(const f32x4*)(src + 5 * 128), rh5 = *(const f32x4*)(src + 5 * 128 + 4);
  f32x4 rl6 = *(const f32x4*)(src + 6 * 128), rh6 = *(const f32x4*)(src + 6 * 128 + 4);
  f32x4 rl7 = *(const f32x4*)(src + 7 * 128), rh7 = *(const f32x4*)(src + 7 * 128 + 4);

  // Named packed accumulators (no arrays).
  f32x2 z = {0.f, 0.f};
  f32x2 d4p0 = z, d4p1 = z, d4p2 = z, d4p3 = z;
  f32x2 d3p0 = z, d3p1 = z, d3p2 = z, d3p3 = z, e3 = z;
  f32x2 d2p0 = z, d2p1 = z, d2p2 = z, d2p3 = z, e2 = z;
  f32x2 d1p0 = z, d1p1 = z, d1p2 = z, d1p3 = z, e1 = z;
  f32x2 d0p0 = z, d0p1 = z, s0 = z;
  f32x2 eDummy = z;

  // Single row sweep: at row i update D0(i,i), D1(i,i-1) ... D4(i,i-4).
  step0(rl0, rh0, d0p0, d0p1, s0);

  step0(rl1, rh1, d0p0, d0p1, s0);
  stepW<true>(rl1, rh1, rl0, rh0, d1p0, d1p1, d1p2, d1p3, e1);

  step0(rl2, rh2, d0p0, d0p1, s0);
  stepW<true>(rl2, rh2, rl1, rh1, d1p0, d1p1, d1p2, d1p3, e1);
  stepW<true>(rl2, rh2, rl0, rh0, d2p0, d2p1, d2p2, d2p3, e2);

  step0(rl3, rh3, d0p0, d0p1, s0);
  stepW<true>(rl3, rh3, rl2, rh2, d1p0, d1p1, d1p2, d1p3, e1);
  stepW<true>(rl3, rh3, rl1, rh1, d2p0, d2p1, d2p2, d2p3, e2);
  stepW<true>(rl3, rh3, rl0, rh0, d3p0, d3p1, d3p2, d3p3, e3);

  step0(rl4, rh4, d0p0, d0p1, s0);
  stepW<true>(rl4, rh4, rl3, rh3, d1p0, d1p1, d1p2, d1p3, e1);
  stepW<true>(rl4, rh4, rl2, rh2, d2p0, d2p1, d2p2, d2p3, e2);
  stepW<true>(rl4, rh4, rl1, rh1, d3p0, d3p1, d3p2, d3p3, e3);
  stepW<false>(rl4, rh4, rl0, rh0, d4p0, d4p1, d4p2, d4p3, eDummy);

  step0(rl5, rh5, d0p0, d0p1, s0);
  stepW<true>(rl5, rh5, rl4, rh4, d1p0, d1p1, d1p2, d1p3, e1);
  stepW<true>(rl5, rh5, rl3, rh3, d2p0, d2p1, d2p2, d2p3, e2);
  stepW<true>(rl5, rh5, rl2, rh2, d3p0, d3p1, d3p2, d3p3, e3);
  stepW<false>(rl5, rh5, rl1, rh1, d4p0, d4p1, d4p2, d4p3, eDummy);

  step0(rl6, rh6, d0p0, d0p1, s0);
  stepW<true>(rl6, rh6, rl5, rh5, d1p0, d1p1, d1p2, d1p3, e1);
  stepW<true>(rl6, rh6, rl4, rh4, d2p0, d2p1, d2p2, d2p3, e2);
  stepW<true>(rl6, rh6, rl3, rh3, d3p0, d3p1, d3p2, d3p3, e3);
  stepW<false>(rl6, rh6, rl2, rh2, d4p0, d4p1, d4p2, d4p3, eDummy);

  step0(rl7, rh7, d0p0, d0p1, s0);
  stepW<true>(rl7, rh7, rl6, rh6, d1p0, d1p1, d1p2, d1p3, e1);
  stepW<true>(rl7, rh7, rl5, rh5, d2p0, d2p1, d2p2, d2p3, e2);
  stepW<true>(rl7, rh7, rl4, rh4, d3p0, d3p1, d3p2, d3p3, e3);
  stepW<false>(rl7, rh7, rl3, rh3, d4p0, d4p1, d4p2, d4p3, eDummy);

  const float ev1 = e1.x + e1.y;
  const float ev2 = e2.x + e2.y;
  const float ev3 = e3.x + e3.y;
  const float a4  = s0.x + s0.y;

#define LDS_ST(e4, A, B, C, Dv)                                             \
  do {                                                                      \
    f32x4 v_ = {A, B, C, Dv};                                               \
    *reinterpret_cast<f32x4*>(wbase + (((e4) ^ sw) << 2)) = v_;             \
  } while (0)

  if (valid) {
    // row 0 (oy=0, dy=-4)
    LDS_ST(0,  d4p0.x, d4p0.y, d4p1.x, d4p1.y);
    LDS_ST(1,  d4p2.x, d4p2.y, d4p3.x, d4p3.y);
    // row 1 (dy=-3) + mirror row 7
    LDS_ST(2,  d3p0.x, d3p0.y, d3p1.x, d3p1.y);
    LDS_ST(3,  d3p2.x, d3p2.y, d3p3.x, d3p3.y);
    LDS_ST(14, ev3,    d3p3.y, d3p3.x, d3p2.y);
    LDS_ST(15, d3p2.x, d3p1.y, d3p1.x, d3p0.y);
    // row 2 (dy=-2) + mirror row 6
    LDS_ST(4,  d2p0.x, d2p0.y, d2p1.x, d2p1.y);
    LDS_ST(5,  d2p2.x, d2p2.y, d2p3.x, d2p3.y);
    LDS_ST(12, ev2,    d2p3.y, d2p3.x, d2p2.y);
    LDS_ST(13, d2p2.x, d2p1.y, d2p1.x, d2p0.y);
    // row 3 (dy=-1) + mirror row 5
    LDS_ST(6,  d1p0.x, d1p0.y, d1p1.x, d1p1.y);
    LDS_ST(7,  d1p2.x, d1p2.y, d1p3.x, d1p3.y);
    LDS_ST(10, ev1,    d1p3.y, d1p3.x, d1p2.y);
    LDS_ST(11, d1p2.x, d1p1.y, d1p1.x, d1p0.y);
    // row 4 (dy=0, self-mirrored)
    LDS_ST(8,  d0p0.x, d0p0.y, d0p1.x, d0p1.y);
    LDS_ST(9,  a4,     d0p1.y, d0p1.x, d0p0.y);
  }
#undef LDS_ST

  // NO __syncthreads: each wave reads back only its OWN two LDS planes
  // (same-wave ds ordering is compiler-enforced via lgkmcnt). Each wave
  // streams its 2 output rows: 64 lanes x 16 B consecutive = full lines.
#pragma unroll
  for (int r = 0; r < 2; ++r) {
    const int hrow = hp * 2 + r;
    if (hrow >= NH) continue;  // wave-uniform (only hp=15, r=1)
    float* orun = out + (size_t)(bc * NH + hrow) * (NW * 64);
    for (int idx = lane; idx < NW * 16; idx += 64) {
      const int ww = idx >> 4;
      const int e4 = idx & 15;
      f32x4 v = *reinterpret_cast<const f32x4*>(&lds[2 * g + r][ww][(e4 ^ (ww & 7)) << 2]);
      *reinterpret_cast<f32x4*>(orun + (size_t)idx * 4) = v;
    }
  }
}

extern "C" void kernel_launch(void* const* d_in, const int* in_sizes, int n_in,
                              void* d_out, int out_size, void* d_ws, size_t ws_size,
                              hipStream_t stream) {
  const float* x = (const float*)d_in[0];
  float* out = (float*)d_out;
  // 512 bc-planes x 4 hp-quads
  lacorr2d_kernel<<<512 * 4, 256, 0, stream>>>(x, out);
}